// Round 1
// baseline (403.838 us; speedup 1.0000x reference)
//
#include <hip/hip_runtime.h>
#include <stdint.h>

// ---------------- problem constants (from reference) ----------------
#define DIN   4096
#define DOUT  4096
#define RANK  16
#define MTOT  8192            // 4 * 2048
#define LSCALE 2.0f           // alpha/rank = 32/16

typedef unsigned short u16;
typedef __bf16 bf16x8 __attribute__((ext_vector_type(8)));
typedef float  f32x4  __attribute__((ext_vector_type(4)));
typedef u16    u16x8  __attribute__((ext_vector_type(8)));

__device__ __forceinline__ u16 f2bf(float f) {
    uint32_t u = __builtin_bit_cast(uint32_t, f);
    u = (u + 0x7FFFu + ((u >> 16) & 1u)) >> 16;   // RNE
    return (u16)u;
}

__device__ __forceinline__ u16x8 pack8(f32x4 a, f32x4 b) {
    u16x8 o;
    o[0] = f2bf(a[0]); o[1] = f2bf(a[1]); o[2] = f2bf(a[2]); o[3] = f2bf(a[3]);
    o[4] = f2bf(b[0]); o[5] = f2bf(b[1]); o[6] = f2bf(b[2]); o[7] = f2bf(b[3]);
    return o;
}

#define GLDS16(g, l) __builtin_amdgcn_global_load_lds( \
    (const __attribute__((address_space(1))) void*)(g), \
    (__attribute__((address_space(3))) void*)(l), 16, 0, 0)

// ---------------- pass 1a: x (f32) -> xb (bf16) ----------------
__global__ __launch_bounds__(256) void k_convert_x(const float* __restrict__ x,
                                                   u16* __restrict__ xb) {
    long i = ((long)blockIdx.x * 256 + threadIdx.x) * 8;
    f32x4 a = *(const f32x4*)(x + i);
    f32x4 b = *(const f32x4*)(x + i + 4);
    *(u16x8*)(xb + i) = pack8(a, b);
}

// ---------------- pass 1b: W_eff = W + scale * B @ A  (bf16) ----------------
__global__ __launch_bounds__(256) void k_build_weff(const float* __restrict__ W,
                                                    const float* __restrict__ A,
                                                    const float* __restrict__ B,
                                                    u16* __restrict__ wb) {
    long t = (long)blockIdx.x * 256 + threadIdx.x;
    long i = t * 8;
    int o = (int)(i >> 12);        // / DIN
    int d = (int)(i & (DIN - 1));
    float sB[RANK];
#pragma unroll
    for (int r = 0; r < RANK; ++r) sB[r] = B[o * RANK + r] * LSCALE;
    f32x4 w0 = *(const f32x4*)(W + i);
    f32x4 w1 = *(const f32x4*)(W + i + 4);
#pragma unroll
    for (int r = 0; r < RANK; ++r) {
        f32x4 a0 = *(const f32x4*)(A + (long)r * DIN + d);
        f32x4 a1 = *(const f32x4*)(A + (long)r * DIN + d + 4);
        w0 += a0 * sB[r];
        w1 += a1 * sB[r];
    }
    *(u16x8*)(wb + i) = pack8(w0, w1);
}

// ---------------- main GEMM: out = xb @ wb^T + bias ----------------
// 128x128 tile, BK=32, 4 waves (each 64x64 = 4x4 frags of 16x16),
// global_load_lds width-16 staging, 2-barrier K-loop (m97 structure).
__global__ __launch_bounds__(256) void k_gemm_ws(const u16* __restrict__ xb,
                                                 const u16* __restrict__ wb,
                                                 const float* __restrict__ bias,
                                                 float* __restrict__ out) {
    constexpr int BM = 128, BN = 128, BK = 32, K = DIN, N = DOUT;
    __shared__ __align__(16) u16 As[BM * BK];
    __shared__ __align__(16) u16 Bs[BN * BK];

    const int tid = threadIdx.x;
    const int bm = blockIdx.y * BM;
    const int bn = blockIdx.x * BN;
    const int lane = tid & 63;
    const int wid  = tid >> 6;
    const int wr = wid >> 1, wc = wid & 1;     // wave tile origin (wr*64, wc*64)
    const int lrow = lane & 15;
    const int kgrp = lane >> 4;                // 0..3

    // staging: chunk c (0..511) -> tile row c>>2, k-subchunk c&3 (8 bf16 = 16B)
    const int c0 = tid, c1 = tid + 256;
    const u16* aS0 = xb + (long)(bm + (c0 >> 2)) * K + (c0 & 3) * 8;
    const u16* aS1 = xb + (long)(bm + (c1 >> 2)) * K + (c1 & 3) * 8;
    const u16* bS0 = wb + (long)(bn + (c0 >> 2)) * K + (c0 & 3) * 8;
    const u16* bS1 = wb + (long)(bn + (c1 >> 2)) * K + (c1 & 3) * 8;
    u16* aD0 = As + c0 * 8;  u16* aD1 = As + c1 * 8;
    u16* bD0 = Bs + c0 * 8;  u16* bD1 = Bs + c1 * 8;

    // fragment read bases
    const u16* aR = As + (wr * 64 + lrow) * BK + kgrp * 8;
    const u16* bR = Bs + (wc * 64 + lrow) * BK + kgrp * 8;

    f32x4 acc[4][4];
#pragma unroll
    for (int i = 0; i < 4; ++i)
#pragma unroll
        for (int j = 0; j < 4; ++j) acc[i][j] = (f32x4){0.f, 0.f, 0.f, 0.f};

    for (int k0 = 0; k0 < K; k0 += BK) {
        if (k0) __syncthreads();
        GLDS16(aS0, aD0); GLDS16(aS1, aD1);
        GLDS16(bS0, bD0); GLDS16(bS1, bD1);
        aS0 += BK; aS1 += BK; bS0 += BK; bS1 += BK;
        __syncthreads();   // drains vmcnt(0) -> tiles resident

        bf16x8 af[4], bf[4];
#pragma unroll
        for (int i = 0; i < 4; ++i) af[i] = *(const bf16x8*)(aR + i * 16 * BK);
#pragma unroll
        for (int j = 0; j < 4; ++j) bf[j] = *(const bf16x8*)(bR + j * 16 * BK);
#pragma unroll
        for (int i = 0; i < 4; ++i)
#pragma unroll
            for (int j = 0; j < 4; ++j)
                acc[i][j] = __builtin_amdgcn_mfma_f32_16x16x32_bf16(af[i], bf[j], acc[i][j], 0, 0, 0);
    }

    // epilogue: + bias, scalar stores (D layout: row=(lane>>4)*4+reg, col=lane&15)
#pragma unroll
    for (int j = 0; j < 4; ++j) {
        const int col = bn + wc * 64 + j * 16 + lrow;
        const float bj = bias[col];
#pragma unroll
        for (int i = 0; i < 4; ++i) {
            const int row0 = bm + wr * 64 + i * 16 + kgrp * 4;
#pragma unroll
            for (int r = 0; r < 4; ++r)
                out[(long)(row0 + r) * N + col] = acc[i][j][r] + bj;
        }
    }
}

// ---------------- fallback: T = scale * x @ A^T  (one wave per row) ----------------
__global__ __launch_bounds__(64) void k_lora_T(const float* __restrict__ x,
                                               const float* __restrict__ A,
                                               float* __restrict__ T) {
    const int m = blockIdx.x;
    const int lane = threadIdx.x;
    const float* xr = x + (long)m * DIN;
    float acc[RANK];
#pragma unroll
    for (int r = 0; r < RANK; ++r) acc[r] = 0.f;
    for (int k = lane * 4; k < DIN; k += 64 * 4) {
        f32x4 xv = *(const f32x4*)(xr + k);
#pragma unroll
        for (int r = 0; r < RANK; ++r) {
            f32x4 av = *(const f32x4*)(A + (long)r * DIN + k);
            acc[r] += xv[0] * av[0] + xv[1] * av[1] + xv[2] * av[2] + xv[3] * av[3];
        }
    }
#pragma unroll
    for (int r = 0; r < RANK; ++r)
        for (int off = 32; off > 0; off >>= 1) acc[r] += __shfl_down(acc[r], off);
    if (lane == 0) {
#pragma unroll
        for (int r = 0; r < RANK; ++r) T[(long)m * RANK + r] = acc[r] * LSCALE;
    }
}

// ---------------- fallback GEMM: f32 sources, reg-staged conversion ----------------
__global__ __launch_bounds__(256) void k_gemm_nows(const float* __restrict__ x,
                                                   const float* __restrict__ W,
                                                   const float* __restrict__ bias,
                                                   const float* __restrict__ T,
                                                   const float* __restrict__ lB,
                                                   float* __restrict__ out) {
    constexpr int BM = 128, BN = 128, BK = 32, K = DIN, N = DOUT;
    __shared__ __align__(16) u16 As[BM * BK];
    __shared__ __align__(16) u16 Bs[BN * BK];

    const int tid = threadIdx.x;
    const int bm = blockIdx.y * BM;
    const int bn = blockIdx.x * BN;
    const int lane = tid & 63;
    const int wid  = tid >> 6;
    const int wr = wid >> 1, wc = wid & 1;
    const int lrow = lane & 15;
    const int kgrp = lane >> 4;

    const int c0 = tid, c1 = tid + 256;
    const float* aS0 = x + (long)(bm + (c0 >> 2)) * K + (c0 & 3) * 8;
    const float* aS1 = x + (long)(bm + (c1 >> 2)) * K + (c1 & 3) * 8;
    const float* bS0 = W + (long)(bn + (c0 >> 2)) * K + (c0 & 3) * 8;
    const float* bS1 = W + (long)(bn + (c1 >> 2)) * K + (c1 & 3) * 8;
    u16* aD0 = As + c0 * 8;  u16* aD1 = As + c1 * 8;
    u16* bD0 = Bs + c0 * 8;  u16* bD1 = Bs + c1 * 8;

    const u16* aR = As + (wr * 64 + lrow) * BK + kgrp * 8;
    const u16* bR = Bs + (wc * 64 + lrow) * BK + kgrp * 8;

    f32x4 acc[4][4];
#pragma unroll
    for (int i = 0; i < 4; ++i)
#pragma unroll
        for (int j = 0; j < 4; ++j) acc[i][j] = (f32x4){0.f, 0.f, 0.f, 0.f};

    for (int k0 = 0; k0 < K; k0 += BK) {
        f32x4 a00 = *(const f32x4*)aS0, a01 = *(const f32x4*)(aS0 + 4);
        f32x4 a10 = *(const f32x4*)aS1, a11 = *(const f32x4*)(aS1 + 4);
        f32x4 b00 = *(const f32x4*)bS0, b01 = *(const f32x4*)(bS0 + 4);
        f32x4 b10 = *(const f32x4*)bS1, b11 = *(const f32x4*)(bS1 + 4);
        aS0 += BK; aS1 += BK; bS0 += BK; bS1 += BK;
        if (k0) __syncthreads();
        *(u16x8*)aD0 = pack8(a00, a01);
        *(u16x8*)aD1 = pack8(a10, a11);
        *(u16x8*)bD0 = pack8(b00, b01);
        *(u16x8*)bD1 = pack8(b10, b11);
        __syncthreads();

        bf16x8 af[4], bf[4];
#pragma unroll
        for (int i = 0; i < 4; ++i) af[i] = *(const bf16x8*)(aR + i * 16 * BK);
#pragma unroll
        for (int j = 0; j < 4; ++j) bf[j] = *(const bf16x8*)(bR + j * 16 * BK);
#pragma unroll
        for (int i = 0; i < 4; ++i)
#pragma unroll
            for (int j = 0; j < 4; ++j)
                acc[i][j] = __builtin_amdgcn_mfma_f32_16x16x32_bf16(af[i], bf[j], acc[i][j], 0, 0, 0);
    }

#pragma unroll
    for (int j = 0; j < 4; ++j) {
        const int col = bn + wc * 64 + j * 16 + lrow;
        const float bj = bias[col];
        float bl[RANK];
#pragma unroll
        for (int q = 0; q < RANK; ++q) bl[q] = lB[(long)col * RANK + q];
#pragma unroll
        for (int i = 0; i < 4; ++i) {
            const int row0 = bm + wr * 64 + i * 16 + kgrp * 4;
#pragma unroll
            for (int r = 0; r < 4; ++r) {
                const int row = row0 + r;
                const float* Trow = T + (long)row * RANK;
                float s = bj;
#pragma unroll
                for (int q = 0; q < RANK; ++q) s += Trow[q] * bl[q];
                out[(long)row * N + col] = acc[i][j][r] + s;
            }
        }
    }
}

extern "C" void kernel_launch(void* const* d_in, const int* in_sizes, int n_in,
                              void* d_out, int out_size, void* d_ws, size_t ws_size,
                              hipStream_t stream) {
    const float* x    = (const float*)d_in[0];
    const float* W    = (const float*)d_in[1];
    const float* bias = (const float*)d_in[2];
    const float* lA   = (const float*)d_in[3];
    const float* lB   = (const float*)d_in[4];
    float* out = (float*)d_out;

    const size_t xb_bytes = (size_t)MTOT * DIN * sizeof(u16);   // 64 MiB
    const size_t wb_bytes = (size_t)DOUT * DIN * sizeof(u16);   // 32 MiB

    if (ws_size >= xb_bytes + wb_bytes) {
        u16* xb = (u16*)d_ws;
        u16* wb = (u16*)((char*)d_ws + xb_bytes);
        k_convert_x <<<(int)((long)MTOT * DIN / 8 / 256), 256, 0, stream>>>(x, xb);
        k_build_weff<<<(int)((long)DOUT * DIN / 8 / 256), 256, 0, stream>>>(W, lA, lB, wb);
        k_gemm_ws   <<<dim3(DOUT / 128, MTOT / 128), 256, 0, stream>>>(xb, wb, bias, out);
    } else {
        float* T = (float*)d_ws;   // 512 KiB
        k_lora_T   <<<MTOT, 64, 0, stream>>>(x, lA, T);
        k_gemm_nows<<<dim3(DOUT / 128, MTOT / 128), 256, 0, stream>>>(x, W, bias, T, lB, out);
    }
}

// Round 2
// 343.067 us; speedup vs baseline: 1.1771x; 1.1771x over previous
//
#include <hip/hip_runtime.h>
#include <stdint.h>

// ---------------- problem constants (from reference) ----------------
#define DIN   4096
#define DOUT  4096
#define RANK  16
#define MTOT  8192            // 4 * 2048
#define LSCALE 2.0f           // alpha/rank = 32/16

typedef unsigned short u16;
typedef __bf16 bf16x8 __attribute__((ext_vector_type(8)));
typedef float  f32x4  __attribute__((ext_vector_type(4)));
typedef u16    u16x8  __attribute__((ext_vector_type(8)));

__device__ __forceinline__ u16 f2bf(float f) {
    uint32_t u = __builtin_bit_cast(uint32_t, f);
    u = (u + 0x7FFFu + ((u >> 16) & 1u)) >> 16;   // RNE
    return (u16)u;
}

__device__ __forceinline__ u16x8 pack8(f32x4 a, f32x4 b) {
    u16x8 o;
    o[0] = f2bf(a[0]); o[1] = f2bf(a[1]); o[2] = f2bf(a[2]); o[3] = f2bf(a[3]);
    o[4] = f2bf(b[0]); o[5] = f2bf(b[1]); o[6] = f2bf(b[2]); o[7] = f2bf(b[3]);
    return o;
}

#define GLDS16(g, l) __builtin_amdgcn_global_load_lds( \
    (const __attribute__((address_space(1))) void*)(g), \
    (__attribute__((address_space(3))) void*)(l), 16, 0, 0)

// ---------------- pass 1a: x (f32) -> xb (bf16) ----------------
__global__ __launch_bounds__(256) void k_convert_x(const float* __restrict__ x,
                                                   u16* __restrict__ xb) {
    long i = ((long)blockIdx.x * 256 + threadIdx.x) * 8;
    f32x4 a = *(const f32x4*)(x + i);
    f32x4 b = *(const f32x4*)(x + i + 4);
    *(u16x8*)(xb + i) = pack8(a, b);
}

// ---------------- pass 1b: W_eff = W + scale * B @ A  (bf16) ----------------
__global__ __launch_bounds__(256) void k_build_weff(const float* __restrict__ W,
                                                    const float* __restrict__ A,
                                                    const float* __restrict__ B,
                                                    u16* __restrict__ wb) {
    long t = (long)blockIdx.x * 256 + threadIdx.x;
    long i = t * 8;
    int o = (int)(i >> 12);        // / DIN
    int d = (int)(i & (DIN - 1));
    float sB[RANK];
#pragma unroll
    for (int r = 0; r < RANK; ++r) sB[r] = B[o * RANK + r] * LSCALE;
    f32x4 w0 = *(const f32x4*)(W + i);
    f32x4 w1 = *(const f32x4*)(W + i + 4);
#pragma unroll
    for (int r = 0; r < RANK; ++r) {
        f32x4 a0 = *(const f32x4*)(A + (long)r * DIN + d);
        f32x4 a1 = *(const f32x4*)(A + (long)r * DIN + d + 4);
        w0 += a0 * sB[r];
        w1 += a1 * sB[r];
    }
    *(u16x8*)(wb + i) = pack8(w0, w1);
}

// ---------------- main GEMM: out = xb @ wb^T + bias ----------------
// 256x256 tile, BK=64, 8 waves (2x4), 128 KiB double-buffered LDS,
// 4-phase K-step with raw barriers + single counted-late vmcnt per tile,
// XOR-swizzled LDS (pre-swizzled gload_lds source), setprio around MFMA.
#define BM 256
#define BN 256
#define BK 64
#define NT (DIN / BK)          // 64 K-tiles

#define MFMA16(d, a, b) d = __builtin_amdgcn_mfma_f32_16x16x32_bf16(a, b, d, 0, 0, 0)
#define RAWBAR() __builtin_amdgcn_s_barrier()

__global__ __launch_bounds__(512, 2) void k_gemm_ws(const u16* __restrict__ xb,
                                                    const u16* __restrict__ wb,
                                                    const float* __restrict__ bias,
                                                    float* __restrict__ out) {
    constexpr int K = DIN, N = DOUT;
    constexpr int AT = BM * BK;        // 16384 u16 = 32 KiB per A tile
    constexpr int BT = BN * BK;
    __shared__ alignas(16) u16 lds[2 * (AT + BT)];   // 128 KiB

    // T1: bijective XCD swizzle (gridDim.x = 512, divisible by 8)
    const int nchunk = gridDim.x >> 3;
    const int bid = blockIdx.x;
    const int wg  = (bid & 7) * nchunk + (bid >> 3);
    const int bm  = (wg & 31) * BM;    // 32 m-tiles; consecutive wg share bn
    const int bn  = (wg >> 5) * BN;    // 16 n-tiles

    const int tid  = threadIdx.x;
    const int lane = tid & 63;
    const int wid  = tid >> 6;         // 0..7
    const int wr   = wid >> 2;         // 0..1  -> rows wr*128..+128
    const int wc   = wid & 3;          // 0..3  -> cols wc*64..+64
    const int lrow = lane & 15;
    const int kgrp = lane >> 4;        // 0..3

    // ---- staging geometry (T2: pre-swizzled global source, linear LDS dest) ----
    // dest granule g = l*512 + tid -> row = g>>3, phys granule = g&7
    // logical k-granule = phys ^ (row&7); row&7 == (tid>>3)&7 for all l
    const int srow = tid >> 3;                       // 0..63
    const int sgl  = (tid & 7) ^ (srow & 7);
    const u16* aSrc = xb + (long)(bm + srow) * K + sgl * 8;
    const u16* bSrc = wb + (long)(bn + srow) * K + sgl * 8;
    u16* const dA0 = lds            + tid * 8;
    u16* const dA1 = lds + AT       + tid * 8;
    u16* const dB0 = lds + 2*AT     + tid * 8;
    u16* const dB1 = lds + 2*AT+BT  + tid * 8;

    // ---- fragment-read geometry (swizzled) ----
    // A frag (m,kk): row = wr*128 + m*16 + lrow, granule = (kk*4+kgrp)^(lrow&7)
    const int gg  = kgrp ^ (lrow & 7);
    const int go0 = gg * 8;            // kk=0
    const int go1 = (gg ^ 4) * 8;      // kk=1
    const u16* const rA0 = lds            + (wr*128 + lrow) * BK;
    const u16* const rA1 = lds + AT       + (wr*128 + lrow) * BK;
    const u16* const rB0 = lds + 2*AT     + (wc*64  + lrow) * BK;
    const u16* const rB1 = lds + 2*AT+BT  + (wc*64  + lrow) * BK;

    f32x4 acc[8][4];
#pragma unroll
    for (int m = 0; m < 8; ++m)
#pragma unroll
        for (int n = 0; n < 4; ++n) acc[m][n] = (f32x4){0.f, 0.f, 0.f, 0.f};

    // ---- prologue: stage tile 0 into buf0, full drain ----
    {
        const u16* s = aSrc;
        GLDS16(s, dA0); GLDS16(s + 64*K, dA0 + 4096);
        GLDS16(s + 128*K, dA0 + 8192); GLDS16(s + 192*K, dA0 + 12288);
        const u16* p = bSrc;
        GLDS16(p, dB0); GLDS16(p + 64*K, dB0 + 4096);
        GLDS16(p + 128*K, dB0 + 8192); GLDS16(p + 192*K, dB0 + 12288);
    }
    asm volatile("s_waitcnt vmcnt(0)" ::: "memory");
    __syncthreads();

    for (int t = 0; t < NT; ++t) {
        const int cur = t & 1;
        const u16* cA = cur ? rA1 : rA0;
        const u16* cB = cur ? rB1 : rB0;
        u16* nA = cur ? dA0 : dA1;
        u16* nB = cur ? dB0 : dB1;
        const int tn = (t + 1) & (NT - 1);   // wraps on last iter (writes unused)

        bf16x8 afL[4][2], afH[4][2], bfA[2][2], bfB[2][2];

        // ============ P1: read loA + bA, stage A(t+1), MFMA Q(loA x bA) ============
#pragma unroll
        for (int m = 0; m < 4; ++m) {
            afL[m][0] = *(const bf16x8*)(cA + m*1024 + go0);
            afL[m][1] = *(const bf16x8*)(cA + m*1024 + go1);
        }
#pragma unroll
        for (int n = 0; n < 2; ++n) {
            bfA[n][0] = *(const bf16x8*)(cB + n*1024 + go0);
            bfA[n][1] = *(const bf16x8*)(cB + n*1024 + go1);
        }
        {
            const u16* s = aSrc + tn * BK;
            GLDS16(s, nA); GLDS16(s + 64*K, nA + 4096);
            GLDS16(s + 128*K, nA + 8192); GLDS16(s + 192*K, nA + 12288);
        }
        RAWBAR();
        __builtin_amdgcn_s_setprio(1);
#pragma unroll
        for (int m = 0; m < 4; ++m)
#pragma unroll
            for (int n = 0; n < 2; ++n) {
                MFMA16(acc[m][n], afL[m][0], bfA[n][0]);
                MFMA16(acc[m][n], afL[m][1], bfA[n][1]);
            }
        __builtin_amdgcn_s_setprio(0);
        RAWBAR();

        // ============ P2: read bB, stage B(t+1), MFMA Q(loA x bB) ============
#pragma unroll
        for (int n = 0; n < 2; ++n) {
            bfB[n][0] = *(const bf16x8*)(cB + (n+2)*1024 + go0);
            bfB[n][1] = *(const bf16x8*)(cB + (n+2)*1024 + go1);
        }
        {
            const u16* s = bSrc + tn * BK;
            GLDS16(s, nB); GLDS16(s + 64*K, nB + 4096);
            GLDS16(s + 128*K, nB + 8192); GLDS16(s + 192*K, nB + 12288);
        }
        RAWBAR();
        __builtin_amdgcn_s_setprio(1);
#pragma unroll
        for (int m = 0; m < 4; ++m)
#pragma unroll
            for (int n = 0; n < 2; ++n) {
                MFMA16(acc[m][n+2], afL[m][0], bfB[n][0]);
                MFMA16(acc[m][n+2], afL[m][1], bfB[n][1]);
            }
        __builtin_amdgcn_s_setprio(0);
        RAWBAR();

        // ============ P3: read hiA, MFMA Q(hiA x bB) ============
#pragma unroll
        for (int m = 0; m < 4; ++m) {
            afH[m][0] = *(const bf16x8*)(cA + (m+4)*1024 + go0);
            afH[m][1] = *(const bf16x8*)(cA + (m+4)*1024 + go1);
        }
        RAWBAR();
        __builtin_amdgcn_s_setprio(1);
#pragma unroll
        for (int m = 0; m < 4; ++m)
#pragma unroll
            for (int n = 0; n < 2; ++n) {
                MFMA16(acc[m+4][n+2], afH[m][0], bfB[n][0]);
                MFMA16(acc[m+4][n+2], afH[m][1], bfB[n][1]);
            }
        __builtin_amdgcn_s_setprio(0);
        RAWBAR();

        // ============ P4: drain staging (issued 2-3 phases ago), MFMA Q(hiA x bA) ============
        asm volatile("s_waitcnt vmcnt(0)" ::: "memory");
        RAWBAR();
        __builtin_amdgcn_s_setprio(1);
#pragma unroll
        for (int m = 0; m < 4; ++m)
#pragma unroll
            for (int n = 0; n < 2; ++n) {
                MFMA16(acc[m+4][n], afH[m][0], bfA[n][0]);
                MFMA16(acc[m+4][n], afH[m][1], bfA[n][1]);
            }
        __builtin_amdgcn_s_setprio(0);
        RAWBAR();
    }

    // ---- epilogue: + bias, store f32 ----
    const int orow = bm + wr*128 + kgrp*4;
    const int ocol = bn + wc*64 + lrow;
#pragma unroll
    for (int n = 0; n < 4; ++n) {
        const float bj = bias[ocol + n*16];
#pragma unroll
        for (int m = 0; m < 8; ++m) {
#pragma unroll
            for (int r = 0; r < 4; ++r)
                out[(long)(orow + m*16 + r) * N + (ocol + n*16)] = acc[m][n][r] + bj;
        }
    }
}

// ---------------- fallback: T = scale * x @ A^T  (one wave per row) ----------------
__global__ __launch_bounds__(64) void k_lora_T(const float* __restrict__ x,
                                               const float* __restrict__ A,
                                               float* __restrict__ T) {
    const int m = blockIdx.x;
    const int lane = threadIdx.x;
    const float* xr = x + (long)m * DIN;
    float acc[RANK];
#pragma unroll
    for (int r = 0; r < RANK; ++r) acc[r] = 0.f;
    for (int k = lane * 4; k < DIN; k += 64 * 4) {
        f32x4 xv = *(const f32x4*)(xr + k);
#pragma unroll
        for (int r = 0; r < RANK; ++r) {
            f32x4 av = *(const f32x4*)(A + (long)r * DIN + k);
            acc[r] += xv[0] * av[0] + xv[1] * av[1] + xv[2] * av[2] + xv[3] * av[3];
        }
    }
#pragma unroll
    for (int r = 0; r < RANK; ++r)
        for (int off = 32; off > 0; off >>= 1) acc[r] += __shfl_down(acc[r], off);
    if (lane == 0) {
#pragma unroll
        for (int r = 0; r < RANK; ++r) T[(long)m * RANK + r] = acc[r] * LSCALE;
    }
}

// ---------------- fallback GEMM: f32 sources, reg-staged conversion ----------------
__global__ __launch_bounds__(256) void k_gemm_nows(const float* __restrict__ x,
                                                   const float* __restrict__ W,
                                                   const float* __restrict__ bias,
                                                   const float* __restrict__ T,
                                                   const float* __restrict__ lB,
                                                   float* __restrict__ out) {
    constexpr int FBM = 128, FBN = 128, FBK = 32, K = DIN, N = DOUT;
    __shared__ __align__(16) u16 As[FBM * FBK];
    __shared__ __align__(16) u16 Bs[FBN * FBK];

    const int tid = threadIdx.x;
    const int bm = blockIdx.y * FBM;
    const int bn = blockIdx.x * FBN;
    const int lane = tid & 63;
    const int wid  = tid >> 6;
    const int wr = wid >> 1, wc = wid & 1;
    const int lrow = lane & 15;
    const int kgrp = lane >> 4;

    const int c0 = tid, c1 = tid + 256;
    const float* aS0 = x + (long)(bm + (c0 >> 2)) * K + (c0 & 3) * 8;
    const float* aS1 = x + (long)(bm + (c1 >> 2)) * K + (c1 & 3) * 8;
    const float* bS0 = W + (long)(bn + (c0 >> 2)) * K + (c0 & 3) * 8;
    const float* bS1 = W + (long)(bn + (c1 >> 2)) * K + (c1 & 3) * 8;
    u16* aD0 = As + c0 * 8;  u16* aD1 = As + c1 * 8;
    u16* bD0 = Bs + c0 * 8;  u16* bD1 = Bs + c1 * 8;

    const u16* aR = As + (wr * 64 + lrow) * FBK + kgrp * 8;
    const u16* bR = Bs + (wc * 64 + lrow) * FBK + kgrp * 8;

    f32x4 acc[4][4];
#pragma unroll
    for (int i = 0; i < 4; ++i)
#pragma unroll
        for (int j = 0; j < 4; ++j) acc[i][j] = (f32x4){0.f, 0.f, 0.f, 0.f};

    for (int k0 = 0; k0 < K; k0 += FBK) {
        f32x4 a00 = *(const f32x4*)aS0, a01 = *(const f32x4*)(aS0 + 4);
        f32x4 a10 = *(const f32x4*)aS1, a11 = *(const f32x4*)(aS1 + 4);
        f32x4 b00 = *(const f32x4*)bS0, b01 = *(const f32x4*)(bS0 + 4);
        f32x4 b10 = *(const f32x4*)bS1, b11 = *(const f32x4*)(bS1 + 4);
        aS0 += FBK; aS1 += FBK; bS0 += FBK; bS1 += FBK;
        if (k0) __syncthreads();
        *(u16x8*)aD0 = pack8(a00, a01);
        *(u16x8*)aD1 = pack8(a10, a11);
        *(u16x8*)bD0 = pack8(b00, b01);
        *(u16x8*)bD1 = pack8(b10, b11);
        __syncthreads();

        bf16x8 af[4], bf[4];
#pragma unroll
        for (int i = 0; i < 4; ++i) af[i] = *(const bf16x8*)(aR + i * 16 * FBK);
#pragma unroll
        for (int j = 0; j < 4; ++j) bf[j] = *(const bf16x8*)(bR + j * 16 * FBK);
#pragma unroll
        for (int i = 0; i < 4; ++i)
#pragma unroll
            for (int j = 0; j < 4; ++j)
                acc[i][j] = __builtin_amdgcn_mfma_f32_16x16x32_bf16(af[i], bf[j], acc[i][j], 0, 0, 0);
    }

#pragma unroll
    for (int j = 0; j < 4; ++j) {
        const int col = bn + wc * 64 + j * 16 + lrow;
        const float bj = bias[col];
        float bl[RANK];
#pragma unroll
        for (int q = 0; q < RANK; ++q) bl[q] = lB[(long)col * RANK + q];
#pragma unroll
        for (int i = 0; i < 4; ++i) {
            const int row0 = bm + wr * 64 + i * 16 + kgrp * 4;
#pragma unroll
            for (int r = 0; r < 4; ++r) {
                const int row = row0 + r;
                const float* Trow = T + (long)row * RANK;
                float s = bj;
#pragma unroll
                for (int q = 0; q < RANK; ++q) s += Trow[q] * bl[q];
                out[(long)row * N + col] = acc[i][j][r] + s;
            }
        }
    }
}

extern "C" void kernel_launch(void* const* d_in, const int* in_sizes, int n_in,
                              void* d_out, int out_size, void* d_ws, size_t ws_size,
                              hipStream_t stream) {
    const float* x    = (const float*)d_in[0];
    const float* W    = (const float*)d_in[1];
    const float* bias = (const float*)d_in[2];
    const float* lA   = (const float*)d_in[3];
    const float* lB   = (const float*)d_in[4];
    float* out = (float*)d_out;

    const size_t xb_bytes = (size_t)MTOT * DIN * sizeof(u16);   // 64 MiB
    const size_t wb_bytes = (size_t)DOUT * DIN * sizeof(u16);   // 32 MiB

    if (ws_size >= xb_bytes + wb_bytes) {
        u16* xb = (u16*)d_ws;
        u16* wb = (u16*)((char*)d_ws + xb_bytes);
        k_convert_x <<<(int)((long)MTOT * DIN / 8 / 256), 256, 0, stream>>>(x, xb);
        k_build_weff<<<(int)((long)DOUT * DIN / 8 / 256), 256, 0, stream>>>(W, lA, lB, wb);
        k_gemm_ws   <<<(MTOT / BM) * (DOUT / BN), 512, 0, stream>>>(xb, wb, bias, out);
    } else {
        float* T = (float*)d_ws;   // 512 KiB
        k_lora_T   <<<MTOT, 64, 0, stream>>>(x, lA, T);
        k_gemm_nows<<<dim3(DOUT / 128, MTOT / 128), 256, 0, stream>>>(x, W, bias, T, lB, out);
    }
}

// Round 3
// 331.100 us; speedup vs baseline: 1.2197x; 1.0361x over previous
//
#include <hip/hip_runtime.h>
#include <stdint.h>

// ---------------- problem constants (from reference) ----------------
#define DIN   4096
#define DOUT  4096
#define RANK  16
#define MTOT  8192            // 4 * 2048
#define LSCALE 2.0f           // alpha/rank = 32/16

typedef unsigned short u16;
typedef __bf16 bf16x8 __attribute__((ext_vector_type(8)));
typedef float  f32x4  __attribute__((ext_vector_type(4)));
typedef u16    u16x8  __attribute__((ext_vector_type(8)));

__device__ __forceinline__ u16 f2bf(float f) {
    uint32_t u = __builtin_bit_cast(uint32_t, f);
    u = (u + 0x7FFFu + ((u >> 16) & 1u)) >> 16;   // RNE
    return (u16)u;
}

__device__ __forceinline__ u16x8 pack8(f32x4 a, f32x4 b) {
    u16x8 o;
    o[0] = f2bf(a[0]); o[1] = f2bf(a[1]); o[2] = f2bf(a[2]); o[3] = f2bf(a[3]);
    o[4] = f2bf(b[0]); o[5] = f2bf(b[1]); o[6] = f2bf(b[2]); o[7] = f2bf(b[3]);
    return o;
}

#define GLDS16(g, l) __builtin_amdgcn_global_load_lds( \
    (const __attribute__((address_space(1))) void*)(g), \
    (__attribute__((address_space(3))) void*)(l), 16, 0, 0)

// ---------------- pass 1a: x (f32) -> xb (bf16) ----------------
__global__ __launch_bounds__(256) void k_convert_x(const float* __restrict__ x,
                                                   u16* __restrict__ xb) {
    long i = ((long)blockIdx.x * 256 + threadIdx.x) * 8;
    f32x4 a = *(const f32x4*)(x + i);
    f32x4 b = *(const f32x4*)(x + i + 4);
    *(u16x8*)(xb + i) = pack8(a, b);
}

// ---------------- pass 1b: W_eff = W + scale * B @ A  (bf16) ----------------
__global__ __launch_bounds__(256) void k_build_weff(const float* __restrict__ W,
                                                    const float* __restrict__ A,
                                                    const float* __restrict__ B,
                                                    u16* __restrict__ wb) {
    long t = (long)blockIdx.x * 256 + threadIdx.x;
    long i = t * 8;
    int o = (int)(i >> 12);        // / DIN
    int d = (int)(i & (DIN - 1));
    float sB[RANK];
#pragma unroll
    for (int r = 0; r < RANK; ++r) sB[r] = B[o * RANK + r] * LSCALE;
    f32x4 w0 = *(const f32x4*)(W + i);
    f32x4 w1 = *(const f32x4*)(W + i + 4);
#pragma unroll
    for (int r = 0; r < RANK; ++r) {
        f32x4 a0 = *(const f32x4*)(A + (long)r * DIN + d);
        f32x4 a1 = *(const f32x4*)(A + (long)r * DIN + d + 4);
        w0 += a0 * sB[r];
        w1 += a1 * sB[r];
    }
    *(u16x8*)(wb + i) = pack8(w0, w1);
}

// ---------------- main GEMM: out = xb @ wb^T + bias ----------------
// 256x256 tile, BK=64, 8 waves. Half-tile deadline-staggered staging with
// COUNTED vmcnt(4) (never 0 in loop): stage order Alo,Blo,Bhi,Ahi; waits at
// ends of P4/P1/P2. Wave m-rows interleave halves: wr owns rows wr*64..+63
// and 128+wr*64..+63; wc owns cols wc*32..+31 and 128+wc*32..+31.
#define BM 256
#define BN 256
#define BK 64
#define NT (DIN / BK)          // 64 K-tiles

#define MFMA16(d, a, b) d = __builtin_amdgcn_mfma_f32_16x16x32_bf16(a, b, d, 0, 0, 0)
#define RAWBAR() __builtin_amdgcn_s_barrier()
#define VMCNT4() asm volatile("s_waitcnt vmcnt(4)" ::: "memory")

__global__ __launch_bounds__(512, 2) void k_gemm_ws(const u16* __restrict__ xb,
                                                    const u16* __restrict__ wb,
                                                    const float* __restrict__ bias,
                                                    float* __restrict__ out) {
    constexpr int K = DIN, N = DOUT;
    __shared__ alignas(16) u16 lds[65536];   // 128 KiB: A0 A1 B0 B1 slabs of 16384 u16

    // T1: bijective XCD swizzle (gridDim.x = 512, divisible by 8)
    const int nchunk = gridDim.x >> 3;
    const int bid = blockIdx.x;
    const int wg  = (bid & 7) * nchunk + (bid >> 3);
    const int bm  = (wg & 31) * BM;    // 32 m-tiles; consecutive wg share bn
    const int bn  = (wg >> 5) * BN;    // 16 n-tiles

    const int tid  = threadIdx.x;
    const int lane = tid & 63;
    const int wid  = tid >> 6;         // 0..7
    const int wr   = wid >> 2;         // 0..1
    const int wc   = wid & 3;          // 0..3
    const int lrow = lane & 15;
    const int kgrp = lane >> 4;        // 0..3

    // ---- staging geometry (T2: pre-swizzled global source, linear LDS dest) ----
    const int srow = tid >> 3;                       // 0..63
    const int sgl  = (tid & 7) ^ (srow & 7);
    const u16* const aSrcB = xb + (long)(bm + srow) * K + sgl * 8;
    const u16* const bSrcB = wb + (long)(bn + srow) * K + sgl * 8;

    // chunk c covers tile rows 64c..64c+63; A[buf] at buf*16384, B[buf] at 32768+buf*16384
#define STAGE_A(c, buf, kt) GLDS16(aSrcB + (long)(64*(c))*K + (kt)*BK, \
                                   lds + (buf)*16384 + (c)*4096 + tid*8)
#define STAGE_B(c, buf, kt) GLDS16(bSrcB + (long)(64*(c))*K + (kt)*BK, \
                                   lds + 32768 + (buf)*16384 + (c)*4096 + tid*8)

    // ---- fragment-read geometry (swizzled) ----
    const int go0 = (kgrp ^ (lrow & 7)) * 8;   // kk=0 granule byte-off/2
    const int go1 = go0 ^ 32;                  // kk=1: granule ^ 4
    const int arL = (wr*64 + lrow) * 64;       // A.lo row base (u16 units)
    const int arH = arL + 128*64;
    const int brL = (wc*32 + lrow) * 64;       // B.lo row base
    const int brH = brL + 128*64;

    f32x4 acc[8][4];
#pragma unroll
    for (int m = 0; m < 8; ++m)
#pragma unroll
        for (int n = 0; n < 4; ++n) acc[m][n] = (f32x4){0.f, 0.f, 0.f, 0.f};

    // ---- prologue: stage tile 0 into buf0 (deadline order), full drain ----
    STAGE_A(0, 0, 0); STAGE_A(1, 0, 0);
    STAGE_B(0, 0, 0); STAGE_B(1, 0, 0);
    STAGE_B(2, 0, 0); STAGE_B(3, 0, 0);
    STAGE_A(2, 0, 0); STAGE_A(3, 0, 0);
    asm volatile("s_waitcnt vmcnt(0)" ::: "memory");
    __syncthreads();

    for (int t = 0; t < NT; ++t) {
        const int cur = t & 1, nxt = cur ^ 1;
        const int tn = (t + 1) & (NT - 1);     // wraps on last iter (unused data)
        const u16* const pA = lds + cur*16384;
        const u16* const pB = lds + 32768 + cur*16384;

        bf16x8 afL[4][2], afH[4][2], bfA[2][2], bfB[2][2];

        // ===== P1: read afL (A.lo) + bfA (B.lo); stage A.lo(t+1); Q(loA x bA) =====
#pragma unroll
        for (int m = 0; m < 4; ++m) {
            afL[m][0] = *(const bf16x8*)(pA + arL + m*1024 + go0);
            afL[m][1] = *(const bf16x8*)(pA + arL + m*1024 + go1);
        }
#pragma unroll
        for (int n = 0; n < 2; ++n) {
            bfA[n][0] = *(const bf16x8*)(pB + brL + n*1024 + go0);
            bfA[n][1] = *(const bf16x8*)(pB + brL + n*1024 + go1);
        }
        STAGE_A(0, nxt, tn); STAGE_A(1, nxt, tn);
        RAWBAR();
        __builtin_amdgcn_s_setprio(1);
#pragma unroll
        for (int m = 0; m < 4; ++m)
#pragma unroll
            for (int n = 0; n < 2; ++n) {
                MFMA16(acc[m][n], afL[m][0], bfA[n][0]);
                MFMA16(acc[m][n], afL[m][1], bfA[n][1]);
            }
        __builtin_amdgcn_s_setprio(0);
        VMCNT4();                 // retires B.hi(t) (staged P3(t-1))
        RAWBAR();

        // ===== P2: read bfB (B.hi); stage B.lo(t+1); Q(loA x bB) =====
#pragma unroll
        for (int n = 0; n < 2; ++n) {
            bfB[n][0] = *(const bf16x8*)(pB + brH + n*1024 + go0);
            bfB[n][1] = *(const bf16x8*)(pB + brH + n*1024 + go1);
        }
        STAGE_B(0, nxt, tn); STAGE_B(1, nxt, tn);
        RAWBAR();
        __builtin_amdgcn_s_setprio(1);
#pragma unroll
        for (int m = 0; m < 4; ++m)
#pragma unroll
            for (int n = 0; n < 2; ++n) {
                MFMA16(acc[m][n+2], afL[m][0], bfB[n][0]);
                MFMA16(acc[m][n+2], afL[m][1], bfB[n][1]);
            }
        __builtin_amdgcn_s_setprio(0);
        VMCNT4();                 // retires A.hi(t) (staged P4(t-1))
        RAWBAR();

        // ===== P3: read afH (A.hi); stage B.hi(t+1); Q(hiA x bB) =====
#pragma unroll
        for (int m = 0; m < 4; ++m) {
            afH[m][0] = *(const bf16x8*)(pA + arH + m*1024 + go0);
            afH[m][1] = *(const bf16x8*)(pA + arH + m*1024 + go1);
        }
        STAGE_B(2, nxt, tn); STAGE_B(3, nxt, tn);
        RAWBAR();
        __builtin_amdgcn_s_setprio(1);
#pragma unroll
        for (int m = 0; m < 4; ++m)
#pragma unroll
            for (int n = 0; n < 2; ++n) {
                MFMA16(acc[m+4][n+2], afH[m][0], bfB[n][0]);
                MFMA16(acc[m+4][n+2], afH[m][1], bfB[n][1]);
            }
        __builtin_amdgcn_s_setprio(0);
        RAWBAR();                 // no wait

        // ===== P4: stage A.hi(t+1); Q(hiA x bA) =====
        STAGE_A(2, nxt, tn); STAGE_A(3, nxt, tn);
        RAWBAR();
        __builtin_amdgcn_s_setprio(1);
#pragma unroll
        for (int m = 0; m < 4; ++m)
#pragma unroll
            for (int n = 0; n < 2; ++n) {
                MFMA16(acc[m+4][n], afH[m][0], bfA[n][0]);
                MFMA16(acc[m+4][n], afH[m][1], bfA[n][1]);
            }
        __builtin_amdgcn_s_setprio(0);
        VMCNT4();                 // retires A.lo(t+1), B.lo(t+1)
        RAWBAR();
    }
    asm volatile("s_waitcnt vmcnt(0)" ::: "memory");   // drain wrapped prefetch

    // ---- epilogue: + bias, store f32 ----
    const int orow = bm + wr*64 + kgrp*4;
    const int ocol = bn + wc*32 + lrow;
#pragma unroll
    for (int n = 0; n < 4; ++n) {
        const int col = ocol + (n & 1)*16 + (n >> 1)*128;
        const float bj = bias[col];
#pragma unroll
        for (int m = 0; m < 8; ++m) {
            const int row = orow + (m & 3)*16 + (m >> 2)*128;
#pragma unroll
            for (int r = 0; r < 4; ++r)
                out[(long)(row + r) * N + col] = acc[m][n][r] + bj;
        }
    }
}

// ---------------- fallback: T = scale * x @ A^T  (one wave per row) ----------------
__global__ __launch_bounds__(64) void k_lora_T(const float* __restrict__ x,
                                               const float* __restrict__ A,
                                               float* __restrict__ T) {
    const int m = blockIdx.x;
    const int lane = threadIdx.x;
    const float* xr = x + (long)m * DIN;
    float acc[RANK];
#pragma unroll
    for (int r = 0; r < RANK; ++r) acc[r] = 0.f;
    for (int k = lane * 4; k < DIN; k += 64 * 4) {
        f32x4 xv = *(const f32x4*)(xr + k);
#pragma unroll
        for (int r = 0; r < RANK; ++r) {
            f32x4 av = *(const f32x4*)(A + (long)r * DIN + k);
            acc[r] += xv[0] * av[0] + xv[1] * av[1] + xv[2] * av[2] + xv[3] * av[3];
        }
    }
#pragma unroll
    for (int r = 0; r < RANK; ++r)
        for (int off = 32; off > 0; off >>= 1) acc[r] += __shfl_down(acc[r], off);
    if (lane == 0) {
#pragma unroll
        for (int r = 0; r < RANK; ++r) T[(long)m * RANK + r] = acc[r] * LSCALE;
    }
}

// ---------------- fallback GEMM: f32 sources, reg-staged conversion ----------------
__global__ __launch_bounds__(256) void k_gemm_nows(const float* __restrict__ x,
                                                   const float* __restrict__ W,
                                                   const float* __restrict__ bias,
                                                   const float* __restrict__ T,
                                                   const float* __restrict__ lB,
                                                   float* __restrict__ out) {
    constexpr int FBM = 128, FBN = 128, FBK = 32, K = DIN, N = DOUT;
    __shared__ __align__(16) u16 As[FBM * FBK];
    __shared__ __align__(16) u16 Bs[FBN * FBK];

    const int tid = threadIdx.x;
    const int bm = blockIdx.y * FBM;
    const int bn = blockIdx.x * FBN;
    const int lane = tid & 63;
    const int wid  = tid >> 6;
    const int wr = wid >> 1, wc = wid & 1;
    const int lrow = lane & 15;
    const int kgrp = lane >> 4;

    const int c0 = tid, c1 = tid + 256;
    const float* aS0 = x + (long)(bm + (c0 >> 2)) * K + (c0 & 3) * 8;
    const float* aS1 = x + (long)(bm + (c1 >> 2)) * K + (c1 & 3) * 8;
    const float* bS0 = W + (long)(bn + (c0 >> 2)) * K + (c0 & 3) * 8;
    const float* bS1 = W + (long)(bn + (c1 >> 2)) * K + (c1 & 3) * 8;
    u16* aD0 = As + c0 * 8;  u16* aD1 = As + c1 * 8;
    u16* bD0 = Bs + c0 * 8;  u16* bD1 = Bs + c1 * 8;

    const u16* aR = As + (wr * 64 + lrow) * FBK + kgrp * 8;
    const u16* bR = Bs + (wc * 64 + lrow) * FBK + kgrp * 8;

    f32x4 acc[4][4];
#pragma unroll
    for (int i = 0; i < 4; ++i)
#pragma unroll
        for (int j = 0; j < 4; ++j) acc[i][j] = (f32x4){0.f, 0.f, 0.f, 0.f};

    for (int k0 = 0; k0 < K; k0 += FBK) {
        f32x4 a00 = *(const f32x4*)aS0, a01 = *(const f32x4*)(aS0 + 4);
        f32x4 a10 = *(const f32x4*)aS1, a11 = *(const f32x4*)(aS1 + 4);
        f32x4 b00 = *(const f32x4*)bS0, b01 = *(const f32x4*)(bS0 + 4);
        f32x4 b10 = *(const f32x4*)bS1, b11 = *(const f32x4*)(bS1 + 4);
        aS0 += FBK; aS1 += FBK; bS0 += FBK; bS1 += FBK;
        if (k0) __syncthreads();
        *(u16x8*)aD0 = pack8(a00, a01);
        *(u16x8*)aD1 = pack8(a10, a11);
        *(u16x8*)bD0 = pack8(b00, b01);
        *(u16x8*)bD1 = pack8(b10, b11);
        __syncthreads();

        bf16x8 af[4], bf[4];
#pragma unroll
        for (int i = 0; i < 4; ++i) af[i] = *(const bf16x8*)(aR + i * 16 * FBK);
#pragma unroll
        for (int j = 0; j < 4; ++j) bf[j] = *(const bf16x8*)(bR + j * 16 * FBK);
#pragma unroll
        for (int i = 0; i < 4; ++i)
#pragma unroll
            for (int j = 0; j < 4; ++j)
                acc[i][j] = __builtin_amdgcn_mfma_f32_16x16x32_bf16(af[i], bf[j], acc[i][j], 0, 0, 0);
    }

#pragma unroll
    for (int j = 0; j < 4; ++j) {
        const int col = bn + wc * 64 + j * 16 + lrow;
        const float bj = bias[col];
        float bl[RANK];
#pragma unroll
        for (int q = 0; q < RANK; ++q) bl[q] = lB[(long)col * RANK + q];
#pragma unroll
        for (int i = 0; i < 4; ++i) {
            const int row0 = bm + wr * 64 + i * 16 + kgrp * 4;
#pragma unroll
            for (int r = 0; r < 4; ++r) {
                const int row = row0 + r;
                const float* Trow = T + (long)row * RANK;
                float s = bj;
#pragma unroll
                for (int q = 0; q < RANK; ++q) s += Trow[q] * bl[q];
                out[(long)row * N + col] = acc[i][j][r] + s;
            }
        }
    }
}

extern "C" void kernel_launch(void* const* d_in, const int* in_sizes, int n_in,
                              void* d_out, int out_size, void* d_ws, size_t ws_size,
                              hipStream_t stream) {
    const float* x    = (const float*)d_in[0];
    const float* W    = (const float*)d_in[1];
    const float* bias = (const float*)d_in[2];
    const float* lA   = (const float*)d_in[3];
    const float* lB   = (const float*)d_in[4];
    float* out = (float*)d_out;

    const size_t xb_bytes = (size_t)MTOT * DIN * sizeof(u16);   // 64 MiB
    const size_t wb_bytes = (size_t)DOUT * DIN * sizeof(u16);   // 32 MiB

    if (ws_size >= xb_bytes + wb_bytes) {
        u16* xb = (u16*)d_ws;
        u16* wb = (u16*)((char*)d_ws + xb_bytes);
        k_convert_x <<<(int)((long)MTOT * DIN / 8 / 256), 256, 0, stream>>>(x, xb);
        k_build_weff<<<(int)((long)DOUT * DIN / 8 / 256), 256, 0, stream>>>(W, lA, lB, wb);
        k_gemm_ws   <<<(MTOT / BM) * (DOUT / BN), 512, 0, stream>>>(xb, wb, bias, out);
    } else {
        float* T = (float*)d_ws;   // 512 KiB
        k_lora_T   <<<MTOT, 64, 0, stream>>>(x, lA, T);
        k_gemm_nows<<<dim3(DOUT / 128, MTOT / 128), 256, 0, stream>>>(x, W, bias, T, lB, out);
    }
}